// Round 10
// baseline (4136.979 us; speedup 1.0000x reference)
//
#include <hip/hip_runtime.h>
#include <stdint.h>

#define NB 128
#define NT 2048
#define NI 128
#define NH 1024
#define NO 128

typedef float f32x4 __attribute__((ext_vector_type(4)));
typedef float f32x16 __attribute__((ext_vector_type(16)));

// ---------------------------------------------------------------------------
// W2P: pair-transpose W2 [O][H] -> W2P [H][64] of float2 {W2[j][k], W2[j+64][k]}
// ---------------------------------------------------------------------------
__global__ __launch_bounds__(256) void w2p_kernel(
    const float* __restrict__ W2, float2* __restrict__ W2P)
{
    const int idx = blockIdx.x * 256 + threadIdx.x;  // 0..65535
    const int k = idx >> 6;                          // 0..1023
    const int j = idx & 63;                          // 0..63
    W2P[idx] = make_float2(W2[(size_t)j * NH + k], W2[(size_t)(j + 64) * NH + k]);
}

// 4 FMAs: one weight quad vs 4 consecutive x components of batch j.
#define Q4(WQ, XV, J, A0, A1, A2, A3)                                     \
    do {                                                                  \
        A0 = fmaf(WQ.x, (XV)[(J) + 0], A0);                               \
        A1 = fmaf(WQ.y, (XV)[(J) + 1], A1);                               \
        A2 = fmaf(WQ.z, (XV)[(J) + 2], A2);                               \
        A3 = fmaf(WQ.w, (XV)[(J) + 3], A3);                               \
    } while (0)

// ---------------------------------------------------------------------------
// Phase A: fused GEMM1 + LIF1, batch-4 x k-eighth blocking.
// grid = 512 (32 bq x 16 hg), block = 512 = 8 waves = 8 k-eighths (16 k each)
// of the SAME 64 h (lane = h) and the SAME 4 batches b0..b0+3.
// Rationale (R5/R9 measured): phase A is L1-BW-bound on weight bytes
// (256 KB/CU-t = 2040 cyc). Nb=4 reuse cuts weight traffic 4x -> <=500 cyc,
// VALU becomes the bound (~670 cyc/SIMD-t). x via 4x s_load_dwordx16
// (64 SGPR, proven); weights 4 plain quads (16 VGPR; resident or L1-reload,
// either acceptable). 8-way k-reduce via 2-slot-parity LDS, 1 barrier/t;
// waves 0-3 each finish one batch (8 ds_read_b32, fixed pairwise order,
// LIF + ballot + store).
// ---------------------------------------------------------------------------
__global__ __launch_bounds__(512, 4) void snn_phaseA(
    const float* __restrict__ x, const float* __restrict__ W1,
    const float* __restrict__ b1, uint64_t* __restrict__ s1bits)
{
    const int bq = blockIdx.x >> 4;      // 0..31
    const int hg = blockIdx.x & 15;      // 0..15
    const int kq = __builtin_amdgcn_readfirstlane(threadIdx.x >> 6);  // 0..7
    const int lane = threadIdx.x & 63;
    const int h = hg * 64 + lane;
    const int b0 = bq * 4;

    // 4 weight quads: k = kq*16 .. +15 (16 VGPR; compiler's choice to keep).
    const f32x4* __restrict__ wqp =
        reinterpret_cast<const f32x4*>(W1 + (size_t)h * NI + kq * 16);
    const f32x4 w0 = wqp[0], w1 = wqp[1], w2 = wqp[2], w3 = wqp[3];

    const float bias = b1[h];
    __shared__ float red[2][8][4][64];   // 16 KB: [parity][kq][batch][h-lane]

    const float* __restrict__ xr0 = x + (size_t)(b0 + 0) * NT * NI + kq * 16;
    const float* __restrict__ xr1 = x + (size_t)(b0 + 1) * NT * NI + kq * 16;
    const float* __restrict__ xr2 = x + (size_t)(b0 + 2) * NT * NI + kq * 16;
    const float* __restrict__ xr3 = x + (size_t)(b0 + 3) * NT * NI + kq * 16;

    uint64_t* s1w =
        s1bits + (size_t)(b0 + kq) * (NH / 64) + hg;  // valid for kq<4

    float v = 0.0f;  // LIF state of batch b0+kq (finisher waves kq<4 only)
#pragma unroll 1
    for (int t = 0; t < NT; ++t) {
        f32x16 x0, x1, x2, x3;
        asm volatile("s_load_dwordx16 %0, %1, 0x0" : "=s"(x0) : "s"(xr0));
        asm volatile("s_load_dwordx16 %0, %1, 0x0" : "=s"(x1) : "s"(xr1));
        asm volatile("s_load_dwordx16 %0, %1, 0x0" : "=s"(x2) : "s"(xr2));
        asm volatile("s_load_dwordx16 %0, %1, 0x0" : "=s"(x3) : "s"(xr3));
        asm volatile("s_waitcnt lgkmcnt(0)"
                     : "+s"(x0), "+s"(x1), "+s"(x2), "+s"(x3));
        __builtin_amdgcn_sched_barrier(0);

        float a00 = 0.f, a01 = 0.f, a02 = 0.f, a03 = 0.f;
        float a10 = 0.f, a11 = 0.f, a12 = 0.f, a13 = 0.f;
        float a20 = 0.f, a21 = 0.f, a22 = 0.f, a23 = 0.f;
        float a30 = 0.f, a31 = 0.f, a32 = 0.f, a33 = 0.f;
        Q4(w0, x0, 0, a00, a01, a02, a03);
        Q4(w1, x0, 4, a00, a01, a02, a03);
        Q4(w2, x0, 8, a00, a01, a02, a03);
        Q4(w3, x0, 12, a00, a01, a02, a03);
        Q4(w0, x1, 0, a10, a11, a12, a13);
        Q4(w1, x1, 4, a10, a11, a12, a13);
        Q4(w2, x1, 8, a10, a11, a12, a13);
        Q4(w3, x1, 12, a10, a11, a12, a13);
        Q4(w0, x2, 0, a20, a21, a22, a23);
        Q4(w1, x2, 4, a20, a21, a22, a23);
        Q4(w2, x2, 8, a20, a21, a22, a23);
        Q4(w3, x2, 12, a20, a21, a22, a23);
        Q4(w0, x3, 0, a30, a31, a32, a33);
        Q4(w1, x3, 4, a30, a31, a32, a33);
        Q4(w2, x3, 8, a30, a31, a32, a33);
        Q4(w3, x3, 12, a30, a31, a32, a33);

        const int par = t & 1;
        red[par][kq][0][lane] = (a00 + a01) + (a02 + a03);
        red[par][kq][1][lane] = (a10 + a11) + (a12 + a13);
        red[par][kq][2][lane] = (a20 + a21) + (a22 + a23);
        red[par][kq][3][lane] = (a30 + a31) + (a32 + a33);
        __syncthreads();

        if (kq < 4) {
            const float r0 = red[par][0][kq][lane];
            const float r1 = red[par][1][kq][lane];
            const float r2 = red[par][2][kq][lane];
            const float r3 = red[par][3][kq][lane];
            const float r4 = red[par][4][kq][lane];
            const float r5 = red[par][5][kq][lane];
            const float r6 = red[par][6][kq][lane];
            const float r7 = red[par][7][kq][lane];
            const float h1 =
                (((r0 + r1) + (r2 + r3)) + ((r4 + r5) + (r6 + r7))) + bias;
            v = fmaf(h1 - v, 0.5f, v);  // v += (h1 - v)/tau, tau = 2
            const bool sp = (v >= 1.0f);
            v = sp ? 0.0f : v;
            const unsigned long long m = __ballot(sp);
            if (lane == 0) *s1w = (uint64_t)m;
        }
        s1w += NB * (NH / 64);
        xr0 += NI; xr1 += NI; xr2 += NI; xr3 += NI;
        // red[par] slot is next overwritten at t+2, after barrier(t+1): safe.
    }
}

// ---------------------------------------------------------------------------
// Phase B: sparse GEMM2. One wave per m = t*128+b row; lane covers o = lane
// and o+64. Scalar ff1 loop over 16 mask words; per active k one coalesced
// dwordx2 of W2P[k]. Sparse sum (ascending k) == dense sum exactly.
// ---------------------------------------------------------------------------
__global__ __launch_bounds__(256, 4) void snn_phaseB(
    const uint64_t* __restrict__ s1bits, const float2* __restrict__ W2P,
    float* __restrict__ h2)
{
    const int wv = threadIdx.x >> 6;
    const int lane = threadIdx.x & 63;
    const size_t m = (size_t)blockIdx.x * 4 + wv;  // 0..262143

    const uint64_t* __restrict__ sb = s1bits + m * (NH / 64);
    float a0 = 0.f, a1 = 0.f;

#pragma unroll 1
    for (int wd = 0; wd < NH / 64; ++wd) {
        const uint64_t m64 = sb[wd];
        const uint32_t mlo = (uint32_t)__builtin_amdgcn_readfirstlane((int)(uint32_t)m64);
        const uint32_t mhi = (uint32_t)__builtin_amdgcn_readfirstlane((int)(uint32_t)(m64 >> 32));
        uint64_t msk = ((uint64_t)mhi << 32) | mlo;
        while (msk) {
            const int i = __builtin_ctzll(msk);
            msk &= (msk - 1);
            const size_t k = ((size_t)wd << 6) + i;
            const float2 ww = W2P[k * 64 + lane];
            a0 += ww.x;
            a1 += ww.y;
        }
    }
    h2[m * NO + lane] = a0;
    h2[m * NO + 64 + lane] = a1;
}

// ---------------------------------------------------------------------------
// Phase D: LIF2 scan + decision-window count. 256 blocks of 64 threads,
// unroll 16 for deep load pipelining; lanes <-> consecutive o (coalesced).
// ---------------------------------------------------------------------------
__global__ __launch_bounds__(64) void snn_phaseD(
    const float* __restrict__ h2, const float* __restrict__ b2,
    float* __restrict__ out)
{
    const int idx = blockIdx.x * 64 + threadIdx.x;  // 0..16383
    const int b = idx >> 7;
    const int o = idx & 127;
    const float bias = b2[o];

    const float* __restrict__ p = h2 + (size_t)b * NO + o;
    float v = 0.f, c = 0.f;
#pragma unroll 16
    for (int t = 0; t < NT; ++t) {
        const float hh = p[(size_t)t * NB * NO] + bias;
        v = fmaf(hh - v, 0.5f, v);
        const bool s = (v >= 1.0f);
        v = s ? 0.f : v;
        if (t >= NT / 2) c += s ? 1.f : 0.f;
    }
    out[idx] = c;
}

extern "C" void kernel_launch(void* const* d_in, const int* in_sizes, int n_in,
                              void* d_out, int out_size, void* d_ws,
                              size_t ws_size, hipStream_t stream)
{
    const float* x  = (const float*)d_in[0];
    const float* W1 = (const float*)d_in[1];
    const float* b1 = (const float*)d_in[2];
    const float* W2 = (const float*)d_in[3];
    const float* b2 = (const float*)d_in[4];
    float* out = (float*)d_out;

    // ws layout: [s1bits 33.55 MB][W2P 0.52 MB][h2 134.2 MB]
    uint8_t* ws = (uint8_t*)d_ws;
    uint64_t* s1bits = (uint64_t*)ws;
    float2* W2P = (float2*)(ws + (size_t)NT * NB * (NH / 64) * 8);
    float* h2 = (float*)(ws + (size_t)NT * NB * (NH / 64) * 8 +
                         (size_t)NH * 64 * sizeof(float2));

    w2p_kernel<<<dim3((NH * 64) / 256), dim3(256), 0, stream>>>(W2, W2P);
    snn_phaseA<<<dim3(512), dim3(512), 0, stream>>>(x, W1, b1, s1bits);
    snn_phaseB<<<dim3((NT * NB) / 4), dim3(256), 0, stream>>>(s1bits, W2P, h2);
    snn_phaseD<<<dim3(256), dim3(64), 0, stream>>>(h2, b2, out);
}